// Round 7
// baseline (598.030 us; speedup 1.0000x reference)
//
#include <hip/hip_runtime.h>
#include <hip/hip_bf16.h>
#include <math.h>

// GCN, CSR built by 2-phase bucket sort (no scattered-line writes):
//   k_bucket4: bin edges by dst>>8 into 391 padded buckets (packed 4B entries,
//     dense per-bucket writes -> L2-resident lines, ~6.4MB effective vs r6's
//     96MB full-line write-through). 4 sub-counters/bucket dilute contention.
//   k_binsort: one block per bucket, LDS count/scan/place -> true CSR eidx +
//     meta{beg,deg,dinv}.
// Convs gather bf16 rows (xbf 128B, z2 64B); GEMMs dense per node; head fused.

#define F 64
#define OUTF 32
#define BCAP 5120          // per-bucket capacity (4 sub-rows x 1280)
#define SUBCAP 1280
#define BN_INV 0.9999950000374997f  // rsqrt(1 + 1e-5)

__device__ __forceinline__ unsigned fenc(float f) {
    unsigned u = __float_as_uint(f);
    return (u & 0x80000000u) ? ~u : (u | 0x80000000u);
}
__device__ __forceinline__ float fdec(unsigned e) {
    return (e & 0x80000000u) ? __uint_as_float(e & 0x7fffffffu) : __uint_as_float(~e);
}
__device__ __forceinline__ unsigned short f2bf(float f) {  // RNE
    unsigned u = __float_as_uint(f);
    return (unsigned short)((u + 0x7fffu + ((u >> 16) & 1u)) >> 16);
}
__device__ __forceinline__ float bf2f(unsigned short h) {
    return __uint_as_float((unsigned)h << 16);
}

// red layout: [0..31] acc_c, [32] esum, [33] min-enc(uint), [34] max-enc(uint)

__global__ void k_fuse(const float* __restrict__ W2, const float* __restrict__ b2,
                       const float* __restrict__ l2w, const float* __restrict__ l2b,
                       float* __restrict__ w2l2, float* __restrict__ b2l2, float* __restrict__ red,
                       int* __restrict__ bcnt, int NBK4) {
    int t = blockIdx.x * blockDim.x + threadIdx.x;  // 2048 threads
    int k = t >> 5, cc = t & 31;
    float o = 0.0f;
    for (int j = 0; j < F; j++) o += W2[k * F + j] * l2w[j * OUTF + cc];
    w2l2[k * OUTF + cc] = o;
    if (t < OUTF) {
        float b = l2b[t];
        for (int j = 0; j < F; j++) b += b2[j] * l2w[j * OUTF + t];
        b2l2[t] = b;
    }
    if (t < 33) red[t] = 0.0f;
    if (t == 33) ((unsigned*)red)[33] = 0xFFFFFFFFu;
    if (t == 34) ((unsigned*)red)[34] = 0u;
    if (t < NBK4) bcnt[t] = 0;
}

__device__ __forceinline__ void bput(int d, int s, int rep, int* bcnt, unsigned* bucket) {
    int b = d >> 8;
    int p = atomicAdd(&bcnt[4 * b + rep], 1);
    if (p < SUBCAP) bucket[(size_t)b * BCAP + rep * SUBCAP + p] = ((unsigned)s << 8) | (unsigned)(d & 255);
}

__global__ void k_bucket4(const int4* __restrict__ src4, const int4* __restrict__ dst4,
                          int* __restrict__ bcnt, unsigned* __restrict__ bucket, int E4) {
    int e = blockIdx.x * blockDim.x + threadIdx.x;
    if (e < E4) {
        int4 s = src4[e], d = dst4[e];
        bput(d.x, s.x, 0, bcnt, bucket);
        bput(d.y, s.y, 1, bcnt, bucket);
        bput(d.z, s.z, 2, bcnt, bucket);
        bput(d.w, s.w, 3, bcnt, bucket);
    }
}
__global__ void k_bucket1(const int* __restrict__ src, const int* __restrict__ dst,
                          int* __restrict__ bcnt, unsigned* __restrict__ bucket, int E) {
    int e = blockIdx.x * blockDim.x + threadIdx.x;
    if (e < E) bput(dst[e], src[e], e & 3, bcnt, bucket);
}

// exclusive scan of per-bucket totals (NBK <= 512)
__global__ void k_bscan(const int* __restrict__ bcnt, int* __restrict__ bbase, int NBK) {
    __shared__ int s[512];
    int t = threadIdx.x;
    int v = 0;
    if (t < NBK) {
        v = min(bcnt[4 * t + 0], SUBCAP) + min(bcnt[4 * t + 1], SUBCAP) +
            min(bcnt[4 * t + 2], SUBCAP) + min(bcnt[4 * t + 3], SUBCAP);
    }
    s[t] = v;
    __syncthreads();
    for (int off = 1; off < 512; off <<= 1) {
        int u = (t >= off) ? s[t - off] : 0;
        __syncthreads();
        s[t] += u;
        __syncthreads();
    }
    if (t < NBK) bbase[t] = s[t] - v;
}

// one block per bucket: LDS count -> scan -> place. Emits CSR eidx + meta{beg,deg,dinv}.
__global__ __launch_bounds__(256) void k_binsort(const unsigned* __restrict__ bucket,
                                                 const int* __restrict__ bcnt, const int* __restrict__ bbase,
                                                 int* __restrict__ eidx, int4* __restrict__ meta, int N) {
    __shared__ unsigned ledge[BCAP];
    __shared__ int lcnt[256], lofs[256], lcur[256], lscan[256];
    int b = blockIdx.x, t = threadIdx.x;
    int c0 = min(bcnt[4 * b + 0], SUBCAP), c1 = min(bcnt[4 * b + 1], SUBCAP);
    int c2 = min(bcnt[4 * b + 2], SUBCAP), c3 = min(bcnt[4 * b + 3], SUBCAP);
    int o1 = c0, o2 = c0 + c1, o3 = c0 + c1 + c2, count = o3 + c3;
    int base = bbase[b];
    const unsigned* brow = bucket + (size_t)b * BCAP;
    for (int j = t; j < c0; j += 256) ledge[j] = brow[j];
    for (int j = t; j < c1; j += 256) ledge[o1 + j] = brow[SUBCAP + j];
    for (int j = t; j < c2; j += 256) ledge[o2 + j] = brow[2 * SUBCAP + j];
    for (int j = t; j < c3; j += 256) ledge[o3 + j] = brow[3 * SUBCAP + j];
    lcnt[t] = 0;
    __syncthreads();
    for (int j = t; j < count; j += 256) atomicAdd(&lcnt[ledge[j] & 255u], 1);
    __syncthreads();
    int deg = lcnt[t];
    lscan[t] = deg;
    __syncthreads();
    for (int off = 1; off < 256; off <<= 1) {
        int u = (t >= off) ? lscan[t - off] : 0;
        __syncthreads();
        lscan[t] += u;
        __syncthreads();
    }
    lofs[t] = lscan[t] - deg;  // exclusive
    lcur[t] = 0;
    int node = (b << 8) + t;
    if (node < N) meta[node] = make_int4(base + lofs[t], deg, __float_as_int(rsqrtf((float)deg + 1.0f)), 0);
    __syncthreads();
    for (int j = t; j < count; j += 256) {
        unsigned v = ledge[j];
        int loc = (int)(v & 255u);
        int p = atomicAdd(&lcur[loc], 1);
        eidx[base + lofs[loc] + p] = (int)(v >> 8);  // writes within bucket's L2-resident window
    }
}

// xbf = bf16(x * dinv), 4 channels per thread
__global__ void k_prescale(const float4* __restrict__ x4, const int4* __restrict__ meta,
                           ushort4* __restrict__ xbf4, int total4) {
    int idx = blockIdx.x * blockDim.x + threadIdx.x;
    if (idx < total4) {
        float di = __int_as_float(meta[idx >> 4].z);
        float4 v = x4[idx];
        ushort4 o;
        o.x = f2bf(v.x * di); o.y = f2bf(v.y * di); o.z = f2bf(v.z * di); o.w = f2bf(v.w * di);
        xbf4[idx] = o;
    }
}

// conv1: t1 = bf16( dinv_i * (sum_nbr xbf[s] + xbf[i]) ). wave = 4 nodes x 16 lanes x 4ch(bf16).
__global__ __launch_bounds__(256) void k_conv1agg(const unsigned short* __restrict__ xbf,
                                                  const int4* __restrict__ meta,
                                                  const int* __restrict__ eidx,
                                                  unsigned short* __restrict__ t1, int N) {
    int tid = threadIdx.x, wave = tid >> 6, lane = tid & 63;
    int g = lane >> 4, gl = lane & 15;
    for (int i0 = (blockIdx.x * 4 + wave) * 4; i0 < N; i0 += gridDim.x * 16) {
        int i = i0 + g;
        int beg = 0, dcnt = 0;
        float di = 0.f;
        float4 acc = make_float4(0.f, 0.f, 0.f, 0.f);
        float4 a1 = make_float4(0.f, 0.f, 0.f, 0.f);
        if (i < N) {
            int4 m = meta[i];
            beg = m.x; dcnt = m.y; di = __int_as_float(m.z);
            ushort4 v = ((const ushort4*)xbf)[(size_t)i * 16 + gl];  // self
            acc.x = bf2f(v.x); acc.y = bf2f(v.y); acc.z = bf2f(v.z); acc.w = bf2f(v.w);
        }
        for (int base = 0; base < dcnt; base += 16) {
            int j = base + gl;
            int ss = (j < dcnt) ? eidx[beg + j] : 0;
            int cnt = min(dcnt - base, 16);
#pragma unroll
            for (int k = 0; k < 16; k += 2) {
                if (k < cnt) {
                    int s = __shfl(ss, (lane & 48) + k, 64);
                    ushort4 v = ((const ushort4*)xbf)[(size_t)s * 16 + gl];
                    acc.x += bf2f(v.x); acc.y += bf2f(v.y); acc.z += bf2f(v.z); acc.w += bf2f(v.w);
                }
                if (k + 1 < cnt) {
                    int s = __shfl(ss, (lane & 48) + k + 1, 64);
                    ushort4 v = ((const ushort4*)xbf)[(size_t)s * 16 + gl];
                    a1.x += bf2f(v.x); a1.y += bf2f(v.y); a1.z += bf2f(v.z); a1.w += bf2f(v.w);
                }
            }
        }
        if (i < N) {
            ushort4 o;
            o.x = f2bf((acc.x + a1.x) * di);
            o.y = f2bf((acc.y + a1.y) * di);
            o.z = f2bf((acc.z + a1.z) * di);
            o.w = f2bf((acc.w + a1.w) * di);
            ((ushort4*)t1)[(size_t)i * 16 + gl] = o;
        }
    }
}

// dense per-node dual GEMM: z2 = bf16( (ReLU(gs*(t1@W1)+bias1)*dinv) @ w2l2 )
__global__ __launch_bounds__(256, 2) void k_z(const unsigned short* __restrict__ t1,
                                              const int4* __restrict__ meta,
                                              const float* __restrict__ W1, const float* __restrict__ b1,
                                              const float* __restrict__ gamma, const float* __restrict__ beta,
                                              const float* __restrict__ w2l2, unsigned short* __restrict__ z2, int N) {
    __shared__ __align__(16) float tb[4][F];
    __shared__ __align__(16) float hb[4][F];
    int tid = threadIdx.x, wave = tid >> 6, lane = tid & 63, cc = lane & 31;
    float gs = gamma[lane] * BN_INV;
    float bias1 = fmaf(b1[lane], gs, beta[lane]);
    float w1reg[F], w2reg[F];
#pragma unroll
    for (int k = 0; k < F; k++) w1reg[k] = W1[k * F + lane] * gs;
#pragma unroll
    for (int k = 0; k < F; k++) w2reg[k] = w2l2[k * OUTF + cc];

    for (int r = blockIdx.x * 4 + wave; r < N; r += gridDim.x * 4) {
        float di = __int_as_float(meta[r].z);
        tb[wave][lane] = bf2f(t1[(size_t)r * F + lane]);
        float o = bias1;
        const float4* t4 = (const float4*)tb[wave];
#pragma unroll
        for (int k4 = 0; k4 < 16; k4++) {
            float4 tv = t4[k4];  // broadcast
            o = fmaf(tv.x, w1reg[4 * k4 + 0], o);
            o = fmaf(tv.y, w1reg[4 * k4 + 1], o);
            o = fmaf(tv.z, w1reg[4 * k4 + 2], o);
            o = fmaf(tv.w, w1reg[4 * k4 + 3], o);
        }
        hb[wave][lane] = fmaxf(o, 0.0f) * di;  // h row
        float z = 0.0f;
        const float4* h4 = (const float4*)hb[wave];
#pragma unroll
        for (int k4 = 0; k4 < 16; k4++) {
            float4 hv = h4[k4];
            z = fmaf(hv.x, w2reg[4 * k4 + 0], z);
            z = fmaf(hv.y, w2reg[4 * k4 + 1], z);
            z = fmaf(hv.z, w2reg[4 * k4 + 2], z);
            z = fmaf(hv.w, w2reg[4 * k4 + 3], z);
        }
        if (lane < 32) z2[(size_t)r * OUTF + lane] = f2bf(z);
    }
}

// conv2: slim gather of bf16 z2 (64 B rows). wave = 8 nodes x 8 lanes x 4ch.
__global__ __launch_bounds__(256) void k_conv2agg(const unsigned short* __restrict__ z2,
                                                  const int4* __restrict__ meta,
                                                  const int* __restrict__ eidx, const float* __restrict__ b2l2,
                                                  float* __restrict__ logits, float* __restrict__ wraw,
                                                  unsigned* __restrict__ redmm, int N) {
    __shared__ float smn[4], smx[4];
    int tid = threadIdx.x, wave = tid >> 6, lane = tid & 63;
    int g = lane >> 3, gl = lane & 7, gbase = lane & 56;
    float4 bvec = ((const float4*)b2l2)[gl];
    float mn = INFINITY, mx = -INFINITY;
    for (int i0 = (blockIdx.x * 4 + wave) * 8; i0 < N; i0 += gridDim.x * 32) {
        int i = i0 + g;
        int beg = 0, dcnt = 0;
        float di = 0.f;
        float4 acc = make_float4(0.f, 0.f, 0.f, 0.f);
        float4 a1 = make_float4(0.f, 0.f, 0.f, 0.f);
        if (i < N) {
            int4 m = meta[i];
            beg = m.x; dcnt = m.y; di = __int_as_float(m.z);
            ushort4 v = ((const ushort4*)(z2 + (size_t)i * OUTF))[gl];  // self
            acc.x = bf2f(v.x); acc.y = bf2f(v.y); acc.z = bf2f(v.z); acc.w = bf2f(v.w);
        }
        for (int base = 0; base < dcnt; base += 8) {
            int j = base + gl;
            int ss = (j < dcnt) ? eidx[beg + j] : 0;
            int cnt = min(dcnt - base, 8);
#pragma unroll
            for (int k = 0; k < 8; k += 2) {
                if (k < cnt) {
                    int s = __shfl(ss, gbase + k, 64);
                    ushort4 v = ((const ushort4*)(z2 + (size_t)s * OUTF))[gl];
                    acc.x += bf2f(v.x); acc.y += bf2f(v.y); acc.z += bf2f(v.z); acc.w += bf2f(v.w);
                }
                if (k + 1 < cnt) {
                    int s = __shfl(ss, gbase + k + 1, 64);
                    ushort4 v = ((const ushort4*)(z2 + (size_t)s * OUTF))[gl];
                    a1.x += bf2f(v.x); a1.y += bf2f(v.y); a1.z += bf2f(v.z); a1.w += bf2f(v.w);
                }
            }
        }
        float4 lg;
        lg.x = fmaf(acc.x + a1.x, di, bvec.x);
        lg.y = fmaf(acc.y + a1.y, di, bvec.y);
        lg.z = fmaf(acc.z + a1.z, di, bvec.z);
        lg.w = fmaf(acc.w + a1.w, di, bvec.w);
        if (i < N) ((float4*)(logits + (size_t)i * OUTF))[gl] = lg;
        // softmax + entropy over 32 logits spread across 8 lanes x 4
        float m4 = fmaxf(fmaxf(lg.x, lg.y), fmaxf(lg.z, lg.w));
        for (int off = 4; off > 0; off >>= 1) m4 = fmaxf(m4, __shfl_xor(m4, off, 8));
        float p0 = expf(lg.x - m4), p1 = expf(lg.y - m4), p2 = expf(lg.z - m4), p3 = expf(lg.w - m4);
        float s4 = p0 + p1 + p2 + p3;
        for (int off = 4; off > 0; off >>= 1) s4 += __shfl_xor(s4, off, 8);
        float inv = 1.0f / s4;
        float t0 = p0 * inv, t1v = p1 * inv, t2v = p2 * inv, t3 = p3 * inv;
        float e4 = t0 * logf(t0 + 1e-9f) + t1v * logf(t1v + 1e-9f) + t2v * logf(t2v + 1e-9f) + t3 * logf(t3 + 1e-9f);
        for (int off = 4; off > 0; off >>= 1) e4 += __shfl_xor(e4, off, 8);
        float w = 1.0f / (-e4 + 1e-10f);
        if (i < N) {
            if (gl == 0) wraw[i] = w;
            mn = fminf(mn, w);
            mx = fmaxf(mx, w);
        }
    }
    for (int off = 32; off > 0; off >>= 1) {
        mn = fminf(mn, __shfl_xor(mn, off, 64));
        mx = fmaxf(mx, __shfl_xor(mx, off, 64));
    }
    if (lane == 0) { smn[wave] = mn; smx[wave] = mx; }
    __syncthreads();
    if (tid == 0) {
        float a = fminf(fminf(smn[0], smn[1]), fminf(smn[2], smn[3]));
        float b = fmaxf(fmaxf(smx[0], smx[1]), fmaxf(smx[2], smx[3]));
        atomicMin(&redmm[33], fenc(a));
        atomicMax(&redmm[34], fenc(b));
    }
}

__global__ __launch_bounds__(256) void k_weight(const float* __restrict__ logits, const float* __restrict__ wraw,
                                                float* __restrict__ red, int N) {
    const unsigned* mm = (const unsigned*)red;
    float mn = fdec(mm[33]), mx = fdec(mm[34]);
    float inv = 1.0f / (mx - mn);
    int c = threadIdx.x & 31;
    int g = threadIdx.x >> 5;  // 8 row-groups
    float acc = 0.0f, es = 0.0f;
    for (int r = blockIdx.x * 8 + g; r < N; r += gridDim.x * 8) {
        float e = expf((wraw[r] - mn) * inv);
        acc += e * logits[(size_t)r * OUTF + c];
        if (c == 0) es += e;
    }
    __shared__ float sa[8][OUTF];
    __shared__ float se[8];
    sa[g][c] = acc;
    if (c == 0) se[g] = es;
    __syncthreads();
    if (g == 0) {
        float t = sa[0][c];
#pragma unroll
        for (int i = 1; i < 8; i++) t += sa[i][c];
        unsafeAtomicAdd(&red[c], t);
        if (c == 0) {
            float u = 0.0f;
#pragma unroll
            for (int i = 0; i < 8; i++) u += se[i];
            unsafeAtomicAdd(&red[32], u);
        }
    }
}

__global__ void k_final(const float* __restrict__ red, const float* __restrict__ w3,
                        const float* __restrict__ b3, float* __restrict__ out) {
    int j = threadIdx.x;  // 64 threads
    float s = red[32];
    float o = b3[j];
#pragma unroll
    for (int cc = 0; cc < OUTF; cc++) o += (red[cc] / s) * w3[cc * F + j];
    out[j] = o;
}

extern "C" void kernel_launch(void* const* d_in, const int* in_sizes, int n_in,
                              void* d_out, int out_size, void* d_ws, size_t ws_size,
                              hipStream_t stream) {
    const float* x     = (const float*)d_in[0];
    const int*   ei    = (const int*)d_in[1];
    const float* W1    = (const float*)d_in[2];
    const float* b1    = (const float*)d_in[3];
    const float* gamma = (const float*)d_in[4];
    const float* beta  = (const float*)d_in[5];
    const float* W2    = (const float*)d_in[6];
    const float* b2    = (const float*)d_in[7];
    const float* l2w   = (const float*)d_in[8];
    const float* l2b   = (const float*)d_in[9];
    const float* l3w   = (const float*)d_in[10];
    const float* l3b   = (const float*)d_in[11];

    int N = in_sizes[0] / F;
    int E = in_sizes[1] / 2;
    const int* src = ei;
    const int* dst = ei + E;
    int NBK = (N + 255) >> 8;  // 391 buckets of 256 nodes

    // workspace layout (16B-aligned chunks)
    char* p = (char*)d_ws;
    int* bcnt = (int*)p;                p += (size_t)NBK * 4 * 4 + 64;
    int* bbase = (int*)p;               p += 512 * 4;
    unsigned* bucket = (unsigned*)p;    p += (size_t)NBK * BCAP * 4;
    int4* meta = (int4*)p;              p += (size_t)N * 16;
    int* eidx = (int*)p;                p += (size_t)E * 4;
    float* red = (float*)p;             p += 64 * 4;
    float* w2l2 = (float*)p;            p += F * OUTF * 4;
    float* b2l2 = (float*)p;            p += OUTF * 4 + 32;
    unsigned short* xbf = (unsigned short*)p;  p += (size_t)N * F * 2;  // aliased by z2
    unsigned short* t1 = (unsigned short*)p;   p += (size_t)N * F * 2;  // aliased by logits
    float* wraw = (float*)p;            p += (size_t)N * 4;
    unsigned short* z2 = xbf;           // xbf dead after conv1agg
    float* logits = (float*)t1;         // t1 dead after k_z

    // setup + bucket sort CSR build
    k_fuse<<<8, 256, 0, stream>>>(W2, b2, l2w, l2b, w2l2, b2l2, red, bcnt, NBK * 4);
    if ((E & 3) == 0) {
        k_bucket4<<<(E / 4 + 255) / 256, 256, 0, stream>>>((const int4*)src, (const int4*)dst, bcnt, bucket, E / 4);
    } else {
        k_bucket1<<<(E + 255) / 256, 256, 0, stream>>>(src, dst, bcnt, bucket, E);
    }
    k_bscan<<<1, 512, 0, stream>>>(bcnt, bbase, NBK);
    k_binsort<<<NBK, 256, 0, stream>>>(bucket, bcnt, bbase, eidx, meta, N);
    k_prescale<<<(N * 16 + 255) / 256, 256, 0, stream>>>((const float4*)x, meta, (ushort4*)xbf, N * 16);

    // convs
    k_conv1agg<<<2048, 256, 0, stream>>>(xbf, meta, eidx, t1, N);
    k_z<<<1024, 256, 0, stream>>>(t1, meta, W1, b1, gamma, beta, w2l2, z2, N);
    k_conv2agg<<<2048, 256, 0, stream>>>(z2, meta, eidx, b2l2, logits, wraw, (unsigned*)red, N);

    // pooling head
    k_weight<<<1024, 256, 0, stream>>>(logits, wraw, red, N);
    k_final<<<1, 64, 0, stream>>>(red, l3w, l3b, (float*)d_out);
}

// Round 8
// 405.355 us; speedup vs baseline: 1.4753x; 1.4753x over previous
//
#include <hip/hip_runtime.h>
#include <hip/hip_bf16.h>
#include <math.h>

// GCN. CSR built by block-privatized 2-pass counting sort (r7 lesson: shared
// bucket fronts/counters bounce across the 8 non-coherent XCD L2s -> full-line
// write-through; privatized cursors make every written line single-writer).
//   k_hist:  per-block LDS histogram over dst>>8 buckets, dense flush.
//   k_hscan: per-bucket prefix across blocks + bucket bases -> absolute cursors.
//   k_place: re-stream chunk, LDS private cursors, packed (src<<8|dloc) writes
//            into block-owned sub-ranges (lines fill completely).
//   k_binsort: per-bucket LDS count/scan/place -> CSR eidx + meta{beg,deg,dinv}.
// Convs gather bf16 rows (xbf 128B, z2 64B); dense dual-GEMM k_z; fused head.

#define F 64
#define OUTF 32
#define PB 128            // edge-partition blocks (privatized sort)
#define LEDGE 5632        // per-bucket LDS capacity (mean 4096, sigma 64)
#define BN_INV 0.9999950000374997f  // rsqrt(1 + 1e-5)

__device__ __forceinline__ unsigned fenc(float f) {
    unsigned u = __float_as_uint(f);
    return (u & 0x80000000u) ? ~u : (u | 0x80000000u);
}
__device__ __forceinline__ float fdec(unsigned e) {
    return (e & 0x80000000u) ? __uint_as_float(e & 0x7fffffffu) : __uint_as_float(~e);
}
__device__ __forceinline__ unsigned short f2bf(float f) {  // RNE
    unsigned u = __float_as_uint(f);
    return (unsigned short)((u + 0x7fffu + ((u >> 16) & 1u)) >> 16);
}
__device__ __forceinline__ float bf2f(unsigned short h) {
    return __uint_as_float((unsigned)h << 16);
}

// red layout: [0..31] acc_c, [32] esum, [33] min-enc(uint), [34] max-enc(uint)

__global__ void k_fuse(const float* __restrict__ W2, const float* __restrict__ b2,
                       const float* __restrict__ l2w, const float* __restrict__ l2b,
                       float* __restrict__ w2l2, float* __restrict__ b2l2, float* __restrict__ red) {
    int t = blockIdx.x * blockDim.x + threadIdx.x;  // 2048 threads
    int k = t >> 5, cc = t & 31;
    float o = 0.0f;
    for (int j = 0; j < F; j++) o += W2[k * F + j] * l2w[j * OUTF + cc];
    w2l2[k * OUTF + cc] = o;
    if (t < OUTF) {
        float b = l2b[t];
        for (int j = 0; j < F; j++) b += b2[j] * l2w[j * OUTF + t];
        b2l2[t] = b;
    }
    if (t < 33) red[t] = 0.0f;
    if (t == 33) ((unsigned*)red)[33] = 0xFFFFFFFFu;
    if (t == 34) ((unsigned*)red)[34] = 0u;
}

// pass 1: per-block LDS histogram of dst>>8 over this block's private chunk
__global__ __launch_bounds__(256) void k_hist(const int* __restrict__ dst, int* __restrict__ hist,
                                              int E, int NBK) {
    __shared__ int lh[512];
    int t = threadIdx.x, blk = blockIdx.x;
    for (int b = t; b < NBK; b += 256) lh[b] = 0;
    __syncthreads();
    int chunk = (E + PB - 1) / PB;
    int beg = blk * chunk, end = min(beg + chunk, E);
    for (int e = beg + t; e < end; e += 256) atomicAdd(&lh[dst[e] >> 8], 1);
    __syncthreads();
    for (int b = t; b < NBK; b += 256) hist[blk * NBK + b] = lh[b];  // dense coalesced
}

// prefix across blocks per bucket (coalesced rows) + bucket bases -> absolute cursors
__global__ void k_hscan(int* __restrict__ hist, int* __restrict__ bbase, int NBK, int E) {
    __shared__ int s[512];
    int t = threadIdx.x;
    int tot = 0;
    if (t < NBK) {
        for (int blk = 0; blk < PB; blk++) {
            int v = hist[blk * NBK + t];  // coalesced across threads
            hist[blk * NBK + t] = tot;
            tot += v;
        }
    }
    s[t] = tot;
    __syncthreads();
    for (int off = 1; off < 512; off <<= 1) {
        int u = (t >= off) ? s[t - off] : 0;
        __syncthreads();
        s[t] += u;
        __syncthreads();
    }
    int excl = s[t] - tot;
    if (t < NBK) {
        bbase[t] = excl;
        if (t == NBK - 1) bbase[NBK] = excl + tot;
        for (int blk = 0; blk < PB; blk++) hist[blk * NBK + t] += excl;
    }
}

// pass 2: private cursors in LDS; every written line has a single writer block
__global__ __launch_bounds__(256) void k_place(const int* __restrict__ src, const int* __restrict__ dst,
                                               const int* __restrict__ hist, unsigned* __restrict__ bucketArr,
                                               int E, int NBK) {
    __shared__ int cur[512];
    int t = threadIdx.x, blk = blockIdx.x;
    for (int b = t; b < NBK; b += 256) cur[b] = hist[blk * NBK + b];
    __syncthreads();
    int chunk = (E + PB - 1) / PB;
    int beg = blk * chunk, end = min(beg + chunk, E);
    for (int e = beg + t; e < end; e += 256) {
        int d = dst[e], sidx = src[e];
        int p = atomicAdd(&cur[d >> 8], 1);
        bucketArr[p] = ((unsigned)sidx << 8) | (unsigned)(d & 255);
    }
}

// one block per bucket: LDS count -> scan -> place. Emits CSR eidx + meta{beg,deg,dinv}.
__global__ __launch_bounds__(256) void k_binsort(const unsigned* __restrict__ bucketArr,
                                                 const int* __restrict__ bbase,
                                                 int* __restrict__ eidx, int4* __restrict__ meta, int N) {
    __shared__ unsigned ledge[LEDGE];
    __shared__ int lcnt[256], lofs[256], lcur[256], lscan[256];
    int b = blockIdx.x, t = threadIdx.x;
    int gb = bbase[b];
    int count = min(bbase[b + 1] - gb, LEDGE);
    for (int j = t; j < count; j += 256) ledge[j] = bucketArr[gb + j];
    lcnt[t] = 0;
    __syncthreads();
    for (int j = t; j < count; j += 256) atomicAdd(&lcnt[ledge[j] & 255u], 1);
    __syncthreads();
    int deg = lcnt[t];
    lscan[t] = deg;
    __syncthreads();
    for (int off = 1; off < 256; off <<= 1) {
        int u = (t >= off) ? lscan[t - off] : 0;
        __syncthreads();
        lscan[t] += u;
        __syncthreads();
    }
    lofs[t] = lscan[t] - deg;  // exclusive
    lcur[t] = 0;
    int node = (b << 8) + t;
    if (node < N) meta[node] = make_int4(gb + lofs[t], deg, __float_as_int(rsqrtf((float)deg + 1.0f)), 0);
    __syncthreads();
    for (int j = t; j < count; j += 256) {
        unsigned v = ledge[j];
        int loc = (int)(v & 255u);
        int p = atomicAdd(&lcur[loc], 1);
        eidx[gb + lofs[loc] + p] = (int)(v >> 8);  // single-writer 16KB window
    }
}

// xbf = bf16(x * dinv), 4 channels per thread
__global__ void k_prescale(const float4* __restrict__ x4, const int4* __restrict__ meta,
                           ushort4* __restrict__ xbf4, int total4) {
    int idx = blockIdx.x * blockDim.x + threadIdx.x;
    if (idx < total4) {
        float di = __int_as_float(meta[idx >> 4].z);
        float4 v = x4[idx];
        ushort4 o;
        o.x = f2bf(v.x * di); o.y = f2bf(v.y * di); o.z = f2bf(v.z * di); o.w = f2bf(v.w * di);
        xbf4[idx] = o;
    }
}

// conv1: t1 = bf16( dinv_i * (sum_nbr xbf[s] + xbf[i]) ). wave = 4 nodes x 16 lanes x 4ch(bf16).
__global__ __launch_bounds__(256) void k_conv1agg(const unsigned short* __restrict__ xbf,
                                                  const int4* __restrict__ meta,
                                                  const int* __restrict__ eidx,
                                                  unsigned short* __restrict__ t1, int N) {
    int tid = threadIdx.x, wave = tid >> 6, lane = tid & 63;
    int g = lane >> 4, gl = lane & 15;
    for (int i0 = (blockIdx.x * 4 + wave) * 4; i0 < N; i0 += gridDim.x * 16) {
        int i = i0 + g;
        int beg = 0, dcnt = 0;
        float di = 0.f;
        float4 acc = make_float4(0.f, 0.f, 0.f, 0.f);
        float4 a1 = make_float4(0.f, 0.f, 0.f, 0.f);
        if (i < N) {
            int4 m = meta[i];
            beg = m.x; dcnt = m.y; di = __int_as_float(m.z);
            ushort4 v = ((const ushort4*)xbf)[(size_t)i * 16 + gl];  // self
            acc.x = bf2f(v.x); acc.y = bf2f(v.y); acc.z = bf2f(v.z); acc.w = bf2f(v.w);
        }
        for (int base = 0; base < dcnt; base += 16) {
            int j = base + gl;
            int ss = (j < dcnt) ? eidx[beg + j] : 0;
            int cnt = min(dcnt - base, 16);
#pragma unroll
            for (int k = 0; k < 16; k += 2) {
                if (k < cnt) {
                    int s = __shfl(ss, (lane & 48) + k, 64);
                    ushort4 v = ((const ushort4*)xbf)[(size_t)s * 16 + gl];
                    acc.x += bf2f(v.x); acc.y += bf2f(v.y); acc.z += bf2f(v.z); acc.w += bf2f(v.w);
                }
                if (k + 1 < cnt) {
                    int s = __shfl(ss, (lane & 48) + k + 1, 64);
                    ushort4 v = ((const ushort4*)xbf)[(size_t)s * 16 + gl];
                    a1.x += bf2f(v.x); a1.y += bf2f(v.y); a1.z += bf2f(v.z); a1.w += bf2f(v.w);
                }
            }
        }
        if (i < N) {
            ushort4 o;
            o.x = f2bf((acc.x + a1.x) * di);
            o.y = f2bf((acc.y + a1.y) * di);
            o.z = f2bf((acc.z + a1.z) * di);
            o.w = f2bf((acc.w + a1.w) * di);
            ((ushort4*)t1)[(size_t)i * 16 + gl] = o;
        }
    }
}

// dense per-node dual GEMM: z2 = bf16( (ReLU(gs*(t1@W1)+bias1)*dinv) @ w2l2 )
__global__ __launch_bounds__(256, 2) void k_z(const unsigned short* __restrict__ t1,
                                              const int4* __restrict__ meta,
                                              const float* __restrict__ W1, const float* __restrict__ b1,
                                              const float* __restrict__ gamma, const float* __restrict__ beta,
                                              const float* __restrict__ w2l2, unsigned short* __restrict__ z2, int N) {
    __shared__ __align__(16) float tb[4][F];
    __shared__ __align__(16) float hb[4][F];
    int tid = threadIdx.x, wave = tid >> 6, lane = tid & 63, cc = lane & 31;
    float gs = gamma[lane] * BN_INV;
    float bias1 = fmaf(b1[lane], gs, beta[lane]);
    float w1reg[F], w2reg[F];
#pragma unroll
    for (int k = 0; k < F; k++) w1reg[k] = W1[k * F + lane] * gs;
#pragma unroll
    for (int k = 0; k < F; k++) w2reg[k] = w2l2[k * OUTF + cc];

    for (int r = blockIdx.x * 4 + wave; r < N; r += gridDim.x * 4) {
        float di = __int_as_float(meta[r].z);
        tb[wave][lane] = bf2f(t1[(size_t)r * F + lane]);
        float o = bias1;
        const float4* t4 = (const float4*)tb[wave];
#pragma unroll
        for (int k4 = 0; k4 < 16; k4++) {
            float4 tv = t4[k4];  // broadcast
            o = fmaf(tv.x, w1reg[4 * k4 + 0], o);
            o = fmaf(tv.y, w1reg[4 * k4 + 1], o);
            o = fmaf(tv.z, w1reg[4 * k4 + 2], o);
            o = fmaf(tv.w, w1reg[4 * k4 + 3], o);
        }
        hb[wave][lane] = fmaxf(o, 0.0f) * di;  // h row
        float z = 0.0f;
        const float4* h4 = (const float4*)hb[wave];
#pragma unroll
        for (int k4 = 0; k4 < 16; k4++) {
            float4 hv = h4[k4];
            z = fmaf(hv.x, w2reg[4 * k4 + 0], z);
            z = fmaf(hv.y, w2reg[4 * k4 + 1], z);
            z = fmaf(hv.z, w2reg[4 * k4 + 2], z);
            z = fmaf(hv.w, w2reg[4 * k4 + 3], z);
        }
        if (lane < 32) z2[(size_t)r * OUTF + lane] = f2bf(z);
    }
}

// conv2: slim gather of bf16 z2 (64 B rows). wave = 8 nodes x 8 lanes x 4ch.
__global__ __launch_bounds__(256) void k_conv2agg(const unsigned short* __restrict__ z2,
                                                  const int4* __restrict__ meta,
                                                  const int* __restrict__ eidx, const float* __restrict__ b2l2,
                                                  float* __restrict__ logits, float* __restrict__ wraw,
                                                  unsigned* __restrict__ redmm, int N) {
    __shared__ float smn[4], smx[4];
    int tid = threadIdx.x, wave = tid >> 6, lane = tid & 63;
    int g = lane >> 3, gl = lane & 7, gbase = lane & 56;
    float4 bvec = ((const float4*)b2l2)[gl];
    float mn = INFINITY, mx = -INFINITY;
    for (int i0 = (blockIdx.x * 4 + wave) * 8; i0 < N; i0 += gridDim.x * 32) {
        int i = i0 + g;
        int beg = 0, dcnt = 0;
        float di = 0.f;
        float4 acc = make_float4(0.f, 0.f, 0.f, 0.f);
        float4 a1 = make_float4(0.f, 0.f, 0.f, 0.f);
        if (i < N) {
            int4 m = meta[i];
            beg = m.x; dcnt = m.y; di = __int_as_float(m.z);
            ushort4 v = ((const ushort4*)(z2 + (size_t)i * OUTF))[gl];  // self
            acc.x = bf2f(v.x); acc.y = bf2f(v.y); acc.z = bf2f(v.z); acc.w = bf2f(v.w);
        }
        for (int base = 0; base < dcnt; base += 8) {
            int j = base + gl;
            int ss = (j < dcnt) ? eidx[beg + j] : 0;
            int cnt = min(dcnt - base, 8);
#pragma unroll
            for (int k = 0; k < 8; k += 2) {
                if (k < cnt) {
                    int s = __shfl(ss, gbase + k, 64);
                    ushort4 v = ((const ushort4*)(z2 + (size_t)s * OUTF))[gl];
                    acc.x += bf2f(v.x); acc.y += bf2f(v.y); acc.z += bf2f(v.z); acc.w += bf2f(v.w);
                }
                if (k + 1 < cnt) {
                    int s = __shfl(ss, gbase + k + 1, 64);
                    ushort4 v = ((const ushort4*)(z2 + (size_t)s * OUTF))[gl];
                    a1.x += bf2f(v.x); a1.y += bf2f(v.y); a1.z += bf2f(v.z); a1.w += bf2f(v.w);
                }
            }
        }
        float4 lg;
        lg.x = fmaf(acc.x + a1.x, di, bvec.x);
        lg.y = fmaf(acc.y + a1.y, di, bvec.y);
        lg.z = fmaf(acc.z + a1.z, di, bvec.z);
        lg.w = fmaf(acc.w + a1.w, di, bvec.w);
        if (i < N) ((float4*)(logits + (size_t)i * OUTF))[gl] = lg;
        // softmax + entropy over 32 logits spread across 8 lanes x 4
        float m4 = fmaxf(fmaxf(lg.x, lg.y), fmaxf(lg.z, lg.w));
        for (int off = 4; off > 0; off >>= 1) m4 = fmaxf(m4, __shfl_xor(m4, off, 8));
        float p0 = expf(lg.x - m4), p1 = expf(lg.y - m4), p2 = expf(lg.z - m4), p3 = expf(lg.w - m4);
        float s4 = p0 + p1 + p2 + p3;
        for (int off = 4; off > 0; off >>= 1) s4 += __shfl_xor(s4, off, 8);
        float inv = 1.0f / s4;
        float t0 = p0 * inv, t1v = p1 * inv, t2v = p2 * inv, t3 = p3 * inv;
        float e4 = t0 * logf(t0 + 1e-9f) + t1v * logf(t1v + 1e-9f) + t2v * logf(t2v + 1e-9f) + t3 * logf(t3 + 1e-9f);
        for (int off = 4; off > 0; off >>= 1) e4 += __shfl_xor(e4, off, 8);
        float w = 1.0f / (-e4 + 1e-10f);
        if (i < N) {
            if (gl == 0) wraw[i] = w;
            mn = fminf(mn, w);
            mx = fmaxf(mx, w);
        }
    }
    for (int off = 32; off > 0; off >>= 1) {
        mn = fminf(mn, __shfl_xor(mn, off, 64));
        mx = fmaxf(mx, __shfl_xor(mx, off, 64));
    }
    if (lane == 0) { smn[wave] = mn; smx[wave] = mx; }
    __syncthreads();
    if (tid == 0) {
        float a = fminf(fminf(smn[0], smn[1]), fminf(smn[2], smn[3]));
        float b = fmaxf(fmaxf(smx[0], smx[1]), fmaxf(smx[2], smx[3]));
        atomicMin(&redmm[33], fenc(a));
        atomicMax(&redmm[34], fenc(b));
    }
}

__global__ __launch_bounds__(256) void k_weight(const float* __restrict__ logits, const float* __restrict__ wraw,
                                                float* __restrict__ red, int N) {
    const unsigned* mm = (const unsigned*)red;
    float mn = fdec(mm[33]), mx = fdec(mm[34]);
    float inv = 1.0f / (mx - mn);
    int c = threadIdx.x & 31;
    int g = threadIdx.x >> 5;  // 8 row-groups
    float acc = 0.0f, es = 0.0f;
    for (int r = blockIdx.x * 8 + g; r < N; r += gridDim.x * 8) {
        float e = expf((wraw[r] - mn) * inv);
        acc += e * logits[(size_t)r * OUTF + c];
        if (c == 0) es += e;
    }
    __shared__ float sa[8][OUTF];
    __shared__ float se[8];
    sa[g][c] = acc;
    if (c == 0) se[g] = es;
    __syncthreads();
    if (g == 0) {
        float t = sa[0][c];
#pragma unroll
        for (int i = 1; i < 8; i++) t += sa[i][c];
        unsafeAtomicAdd(&red[c], t);
        if (c == 0) {
            float u = 0.0f;
#pragma unroll
            for (int i = 0; i < 8; i++) u += se[i];
            unsafeAtomicAdd(&red[32], u);
        }
    }
}

__global__ void k_final(const float* __restrict__ red, const float* __restrict__ w3,
                        const float* __restrict__ b3, float* __restrict__ out) {
    int j = threadIdx.x;  // 64 threads
    float s = red[32];
    float o = b3[j];
#pragma unroll
    for (int cc = 0; cc < OUTF; cc++) o += (red[cc] / s) * w3[cc * F + j];
    out[j] = o;
}

extern "C" void kernel_launch(void* const* d_in, const int* in_sizes, int n_in,
                              void* d_out, int out_size, void* d_ws, size_t ws_size,
                              hipStream_t stream) {
    const float* x     = (const float*)d_in[0];
    const int*   ei    = (const int*)d_in[1];
    const float* W1    = (const float*)d_in[2];
    const float* b1    = (const float*)d_in[3];
    const float* gamma = (const float*)d_in[4];
    const float* beta  = (const float*)d_in[5];
    const float* W2    = (const float*)d_in[6];
    const float* b2    = (const float*)d_in[7];
    const float* l2w   = (const float*)d_in[8];
    const float* l2b   = (const float*)d_in[9];
    const float* l3w   = (const float*)d_in[10];
    const float* l3b   = (const float*)d_in[11];

    int N = in_sizes[0] / F;
    int E = in_sizes[1] / 2;
    const int* src = ei;
    const int* dst = ei + E;
    int NBK = (N + 255) >> 8;  // 391 buckets of 256 nodes (<=512 assumed)

    // workspace layout (16B-aligned chunks)
    char* p = (char*)d_ws;
    int* hist = (int*)p;                p += (size_t)PB * NBK * 4;
    int* bbase = (int*)p;               p += 516 * 4;
    unsigned* bucketArr = (unsigned*)p; p += (size_t)E * 4;
    int4* meta = (int4*)p;              p += (size_t)N * 16;
    int* eidx = (int*)p;                p += (size_t)E * 4;
    float* red = (float*)p;             p += 64 * 4;
    float* w2l2 = (float*)p;            p += F * OUTF * 4;
    float* b2l2 = (float*)p;            p += OUTF * 4 + 32;
    unsigned short* xbf = (unsigned short*)p;  p += (size_t)N * F * 2;  // aliased by z2
    unsigned short* t1 = (unsigned short*)p;   p += (size_t)N * F * 2;  // aliased by logits
    float* wraw = (float*)p;            p += (size_t)N * 4;
    unsigned short* z2 = xbf;           // xbf dead after conv1agg
    float* logits = (float*)t1;         // t1 dead after k_z

    // setup + privatized counting-sort CSR build
    k_fuse<<<8, 256, 0, stream>>>(W2, b2, l2w, l2b, w2l2, b2l2, red);
    k_hist<<<PB, 256, 0, stream>>>(dst, hist, E, NBK);
    k_hscan<<<1, 512, 0, stream>>>(hist, bbase, NBK, E);
    k_place<<<PB, 256, 0, stream>>>(src, dst, hist, bucketArr, E, NBK);
    k_binsort<<<NBK, 256, 0, stream>>>(bucketArr, bbase, eidx, meta, N);
    k_prescale<<<(N * 16 + 255) / 256, 256, 0, stream>>>((const float4*)x, meta, (ushort4*)xbf, N * 16);

    // convs
    k_conv1agg<<<2048, 256, 0, stream>>>(xbf, meta, eidx, t1, N);
    k_z<<<1024, 256, 0, stream>>>(t1, meta, W1, b1, gamma, beta, w2l2, z2, N);
    k_conv2agg<<<2048, 256, 0, stream>>>(z2, meta, eidx, b2l2, logits, wraw, (unsigned*)red, N);

    // pooling head
    k_weight<<<1024, 256, 0, stream>>>(logits, wraw, red, N);
    k_final<<<1, 64, 0, stream>>>(red, l3w, l3b, (float*)d_out);
}

// Round 9
// 370.133 us; speedup vs baseline: 1.6157x; 1.0952x over previous
//
#include <hip/hip_runtime.h>
#include <hip/hip_bf16.h>
#include <math.h>

// GCN. CSR via block-privatized 2-pass counting sort (single-writer lines).
// r9: gathers issue all eidx slot loads upfront (conv1: 32 slots/2 loads,
// conv2: 24 slots/3 loads) + 4 independent accumulator chains -> 1 serialized
// latency chain in the common case (r8: 2-3). k_hscan parallelized
// (per-bucket block scan + tiny totals scan; base-add folded into k_place).

#define F 64
#define OUTF 32
#define PB 128            // edge-partition blocks (privatized sort)
#define LEDGE 5632        // per-bucket LDS capacity (mean 4096)
#define BN_INV 0.9999950000374997f  // rsqrt(1 + 1e-5)

__device__ __forceinline__ unsigned fenc(float f) {
    unsigned u = __float_as_uint(f);
    return (u & 0x80000000u) ? ~u : (u | 0x80000000u);
}
__device__ __forceinline__ float fdec(unsigned e) {
    return (e & 0x80000000u) ? __uint_as_float(e & 0x7fffffffu) : __uint_as_float(~e);
}
__device__ __forceinline__ unsigned short f2bf(float f) {  // RNE
    unsigned u = __float_as_uint(f);
    return (unsigned short)((u + 0x7fffu + ((u >> 16) & 1u)) >> 16);
}
__device__ __forceinline__ float bf2f(unsigned short h) {
    return __uint_as_float((unsigned)h << 16);
}

// red layout: [0..31] acc_c, [32] esum, [33] min-enc(uint), [34] max-enc(uint)

__global__ void k_fuse(const float* __restrict__ W2, const float* __restrict__ b2,
                       const float* __restrict__ l2w, const float* __restrict__ l2b,
                       float* __restrict__ w2l2, float* __restrict__ b2l2, float* __restrict__ red) {
    int t = blockIdx.x * blockDim.x + threadIdx.x;  // 2048 threads
    int k = t >> 5, cc = t & 31;
    float o = 0.0f;
    for (int j = 0; j < F; j++) o += W2[k * F + j] * l2w[j * OUTF + cc];
    w2l2[k * OUTF + cc] = o;
    if (t < OUTF) {
        float b = l2b[t];
        for (int j = 0; j < F; j++) b += b2[j] * l2w[j * OUTF + t];
        b2l2[t] = b;
    }
    if (t < 33) red[t] = 0.0f;
    if (t == 33) ((unsigned*)red)[33] = 0xFFFFFFFFu;
    if (t == 34) ((unsigned*)red)[34] = 0u;
}

// pass 1: per-block LDS histogram of dst>>8 over this block's private chunk
__global__ __launch_bounds__(256) void k_hist(const int* __restrict__ dst, int* __restrict__ hist,
                                              int E, int NBK) {
    __shared__ int lh[512];
    int t = threadIdx.x, blk = blockIdx.x;
    for (int b = t; b < NBK; b += 256) lh[b] = 0;
    __syncthreads();
    int chunk = (E + PB - 1) / PB;
    int beg = blk * chunk, end = min(beg + chunk, E);
    for (int e = beg + t; e < end; e += 256) atomicAdd(&lh[dst[e] >> 8], 1);
    __syncthreads();
    for (int b = t; b < NBK; b += 256) hist[blk * NBK + b] = lh[b];  // dense coalesced
}

// per-bucket exclusive scan across the PB blocks (one block per bucket)
__global__ __launch_bounds__(PB) void k_hscan1(int* __restrict__ hist, int* __restrict__ btot, int NBK) {
    __shared__ int s[PB];
    int b = blockIdx.x, t = threadIdx.x;
    int v = hist[t * NBK + b];
    s[t] = v;
    __syncthreads();
    for (int off = 1; off < PB; off <<= 1) {
        int u = (t >= off) ? s[t - off] : 0;
        __syncthreads();
        s[t] += u;
        __syncthreads();
    }
    hist[t * NBK + b] = s[t] - v;  // exclusive within bucket
    if (t == PB - 1) btot[b] = s[t];
}

// scan bucket totals -> bbase (1 block; NBK <= 512)
__global__ void k_hscan2(const int* __restrict__ btot, int* __restrict__ bbase, int NBK) {
    __shared__ int s[512];
    int t = threadIdx.x;
    int v = (t < NBK) ? btot[t] : 0;
    s[t] = v;
    __syncthreads();
    for (int off = 1; off < 512; off <<= 1) {
        int u = (t >= off) ? s[t - off] : 0;
        __syncthreads();
        s[t] += u;
        __syncthreads();
    }
    if (t < NBK) {
        bbase[t] = s[t] - v;
        if (t == NBK - 1) bbase[NBK] = s[t];
    }
}

// pass 2: private cursors in LDS (hist offset + bucket base); single-writer lines
__global__ __launch_bounds__(256) void k_place(const int* __restrict__ src, const int* __restrict__ dst,
                                               const int* __restrict__ hist, const int* __restrict__ bbase,
                                               unsigned* __restrict__ bucketArr, int E, int NBK) {
    __shared__ int cur[512];
    int t = threadIdx.x, blk = blockIdx.x;
    for (int b = t; b < NBK; b += 256) cur[b] = hist[blk * NBK + b] + bbase[b];
    __syncthreads();
    int chunk = (E + PB - 1) / PB;
    int beg = blk * chunk, end = min(beg + chunk, E);
    for (int e = beg + t; e < end; e += 256) {
        int d = dst[e], sidx = src[e];
        int p = atomicAdd(&cur[d >> 8], 1);
        bucketArr[p] = ((unsigned)sidx << 8) | (unsigned)(d & 255);
    }
}

// one block per bucket: LDS count -> scan -> place. Emits CSR eidx + meta{beg,deg,dinv}.
__global__ __launch_bounds__(256) void k_binsort(const unsigned* __restrict__ bucketArr,
                                                 const int* __restrict__ bbase,
                                                 int* __restrict__ eidx, int4* __restrict__ meta, int N) {
    __shared__ unsigned ledge[LEDGE];
    __shared__ int lcnt[256], lofs[256], lcur[256], lscan[256];
    int b = blockIdx.x, t = threadIdx.x;
    int gb = bbase[b];
    int count = min(bbase[b + 1] - gb, LEDGE);
    for (int j = t; j < count; j += 256) ledge[j] = bucketArr[gb + j];
    lcnt[t] = 0;
    __syncthreads();
    for (int j = t; j < count; j += 256) atomicAdd(&lcnt[ledge[j] & 255u], 1);
    __syncthreads();
    int deg = lcnt[t];
    lscan[t] = deg;
    __syncthreads();
    for (int off = 1; off < 256; off <<= 1) {
        int u = (t >= off) ? lscan[t - off] : 0;
        __syncthreads();
        lscan[t] += u;
        __syncthreads();
    }
    lofs[t] = lscan[t] - deg;  // exclusive
    lcur[t] = 0;
    int node = (b << 8) + t;
    if (node < N) meta[node] = make_int4(gb + lofs[t], deg, __float_as_int(rsqrtf((float)deg + 1.0f)), 0);
    __syncthreads();
    for (int j = t; j < count; j += 256) {
        unsigned v = ledge[j];
        int loc = (int)(v & 255u);
        int p = atomicAdd(&lcur[loc], 1);
        eidx[gb + lofs[loc] + p] = (int)(v >> 8);  // single-writer 16KB window
    }
}

// xbf = bf16(x * dinv), 4 channels per thread
__global__ void k_prescale(const float4* __restrict__ x4, const int4* __restrict__ meta,
                           ushort4* __restrict__ xbf4, int total4) {
    int idx = blockIdx.x * blockDim.x + threadIdx.x;
    if (idx < total4) {
        float di = __int_as_float(meta[idx >> 4].z);
        float4 v = x4[idx];
        ushort4 o;
        o.x = f2bf(v.x * di); o.y = f2bf(v.y * di); o.z = f2bf(v.z * di); o.w = f2bf(v.w * di);
        xbf4[idx] = o;
    }
}

// conv1: t1 = bf16( dinv_i * (sum_nbr xbf[s] + xbf[i]) ). wave = 4 nodes x 16 lanes x 4ch.
// All slot indices loaded upfront (32 slots via 2 loads; P(deg>32)~1e-4), 4 acc chains.
__global__ __launch_bounds__(256) void k_conv1agg(const unsigned short* __restrict__ xbf,
                                                  const int4* __restrict__ meta,
                                                  const int* __restrict__ eidx,
                                                  unsigned short* __restrict__ t1, int N) {
    int tid = threadIdx.x, wave = tid >> 6, lane = tid & 63;
    int g = lane >> 4, gl = lane & 15, gbase = lane & 48;
    for (int i0 = (blockIdx.x * 4 + wave) * 4; i0 < N; i0 += gridDim.x * 16) {
        int i = i0 + g;
        int beg = 0, dcnt = 0;
        float di = 0.f;
        float4 a0 = make_float4(0.f, 0.f, 0.f, 0.f), a1 = a0, a2 = a0, a3 = a0;
        int ss0 = 0, ss1 = 0;
        if (i < N) {
            int4 m = meta[i];
            beg = m.x; dcnt = m.y; di = __int_as_float(m.z);
            ushort4 v = ((const ushort4*)xbf)[(size_t)i * 16 + gl];  // self
            a0.x = bf2f(v.x); a0.y = bf2f(v.y); a0.z = bf2f(v.z); a0.w = bf2f(v.w);
            ss0 = (gl < dcnt) ? eidx[beg + gl] : 0;
            ss1 = (16 + gl < dcnt) ? eidx[beg + 16 + gl] : 0;
        }
#pragma unroll
        for (int k = 0; k < 32; k++) {
            if (k < dcnt) {
                int sv = __shfl((k < 16) ? ss0 : ss1, gbase + (k & 15), 64);
                ushort4 v = ((const ushort4*)xbf)[(size_t)sv * 16 + gl];
                float4* a = (k & 3) == 0 ? &a0 : (k & 3) == 1 ? &a1 : (k & 3) == 2 ? &a2 : &a3;
                a->x += bf2f(v.x); a->y += bf2f(v.y); a->z += bf2f(v.z); a->w += bf2f(v.w);
            }
        }
        for (int base = 32; base < dcnt; base += 16) {  // rare tail
            int j = base + gl;
            int ss = (j < dcnt) ? eidx[beg + j] : 0;
            int cnt = min(dcnt - base, 16);
#pragma unroll
            for (int k = 0; k < 16; k++) {
                if (k < cnt) {
                    int sv = __shfl(ss, gbase + k, 64);
                    ushort4 v = ((const ushort4*)xbf)[(size_t)sv * 16 + gl];
                    float4* a = (k & 3) == 0 ? &a0 : (k & 3) == 1 ? &a1 : (k & 3) == 2 ? &a2 : &a3;
                    a->x += bf2f(v.x); a->y += bf2f(v.y); a->z += bf2f(v.z); a->w += bf2f(v.w);
                }
            }
        }
        if (i < N) {
            ushort4 o;
            o.x = f2bf((a0.x + a1.x + a2.x + a3.x) * di);
            o.y = f2bf((a0.y + a1.y + a2.y + a3.y) * di);
            o.z = f2bf((a0.z + a1.z + a2.z + a3.z) * di);
            o.w = f2bf((a0.w + a1.w + a2.w + a3.w) * di);
            ((ushort4*)t1)[(size_t)i * 16 + gl] = o;
        }
    }
}

// dense per-node dual GEMM: z2 = bf16( (ReLU(gs*(t1@W1)+bias1)*dinv) @ w2l2 )
__global__ __launch_bounds__(256, 2) void k_z(const unsigned short* __restrict__ t1,
                                              const int4* __restrict__ meta,
                                              const float* __restrict__ W1, const float* __restrict__ b1,
                                              const float* __restrict__ gamma, const float* __restrict__ beta,
                                              const float* __restrict__ w2l2, unsigned short* __restrict__ z2, int N) {
    __shared__ __align__(16) float tb[4][F];
    __shared__ __align__(16) float hb[4][F];
    int tid = threadIdx.x, wave = tid >> 6, lane = tid & 63, cc = lane & 31;
    float gs = gamma[lane] * BN_INV;
    float bias1 = fmaf(b1[lane], gs, beta[lane]);
    float w1reg[F], w2reg[F];
#pragma unroll
    for (int k = 0; k < F; k++) w1reg[k] = W1[k * F + lane] * gs;
#pragma unroll
    for (int k = 0; k < F; k++) w2reg[k] = w2l2[k * OUTF + cc];

    for (int r = blockIdx.x * 4 + wave; r < N; r += gridDim.x * 4) {
        float di = __int_as_float(meta[r].z);
        tb[wave][lane] = bf2f(t1[(size_t)r * F + lane]);
        float o = bias1;
        const float4* t4 = (const float4*)tb[wave];
#pragma unroll
        for (int k4 = 0; k4 < 16; k4++) {
            float4 tv = t4[k4];  // broadcast
            o = fmaf(tv.x, w1reg[4 * k4 + 0], o);
            o = fmaf(tv.y, w1reg[4 * k4 + 1], o);
            o = fmaf(tv.z, w1reg[4 * k4 + 2], o);
            o = fmaf(tv.w, w1reg[4 * k4 + 3], o);
        }
        hb[wave][lane] = fmaxf(o, 0.0f) * di;  // h row
        float z = 0.0f;
        const float4* h4 = (const float4*)hb[wave];
#pragma unroll
        for (int k4 = 0; k4 < 16; k4++) {
            float4 hv = h4[k4];
            z = fmaf(hv.x, w2reg[4 * k4 + 0], z);
            z = fmaf(hv.y, w2reg[4 * k4 + 1], z);
            z = fmaf(hv.z, w2reg[4 * k4 + 2], z);
            z = fmaf(hv.w, w2reg[4 * k4 + 3], z);
        }
        if (lane < 32) z2[(size_t)r * OUTF + lane] = f2bf(z);
    }
}

// conv2: slim gather of bf16 z2 (64 B rows). wave = 8 nodes x 8 lanes x 4ch.
// 24 slots upfront via 3 loads (P(deg>24)~2%), 4 acc chains; fused softmax/entropy.
__global__ __launch_bounds__(256) void k_conv2agg(const unsigned short* __restrict__ z2,
                                                  const int4* __restrict__ meta,
                                                  const int* __restrict__ eidx, const float* __restrict__ b2l2,
                                                  float* __restrict__ logits, float* __restrict__ wraw,
                                                  unsigned* __restrict__ redmm, int N) {
    __shared__ float smn[4], smx[4];
    int tid = threadIdx.x, wave = tid >> 6, lane = tid & 63;
    int g = lane >> 3, gl = lane & 7, gbase = lane & 56;
    float4 bvec = ((const float4*)b2l2)[gl];
    float mn = INFINITY, mx = -INFINITY;
    for (int i0 = (blockIdx.x * 4 + wave) * 8; i0 < N; i0 += gridDim.x * 32) {
        int i = i0 + g;
        int beg = 0, dcnt = 0;
        float di = 0.f;
        float4 a0 = make_float4(0.f, 0.f, 0.f, 0.f), a1 = a0, a2 = a0, a3 = a0;
        int ss0 = 0, ss1 = 0, ss2 = 0;
        if (i < N) {
            int4 m = meta[i];
            beg = m.x; dcnt = m.y; di = __int_as_float(m.z);
            ushort4 v = ((const ushort4*)(z2 + (size_t)i * OUTF))[gl];  // self
            a0.x = bf2f(v.x); a0.y = bf2f(v.y); a0.z = bf2f(v.z); a0.w = bf2f(v.w);
            ss0 = (gl < dcnt) ? eidx[beg + gl] : 0;
            ss1 = (8 + gl < dcnt) ? eidx[beg + 8 + gl] : 0;
            ss2 = (16 + gl < dcnt) ? eidx[beg + 16 + gl] : 0;
        }
#pragma unroll
        for (int k = 0; k < 24; k++) {
            if (k < dcnt) {
                int sv = __shfl((k < 8) ? ss0 : (k < 16) ? ss1 : ss2, gbase + (k & 7), 64);
                ushort4 v = ((const ushort4*)(z2 + (size_t)sv * OUTF))[gl];
                float4* a = (k & 3) == 0 ? &a0 : (k & 3) == 1 ? &a1 : (k & 3) == 2 ? &a2 : &a3;
                a->x += bf2f(v.x); a->y += bf2f(v.y); a->z += bf2f(v.z); a->w += bf2f(v.w);
            }
        }
        for (int base = 24; base < dcnt; base += 8) {  // rare tail
            int j = base + gl;
            int ss = (j < dcnt) ? eidx[beg + j] : 0;
            int cnt = min(dcnt - base, 8);
#pragma unroll
            for (int k = 0; k < 8; k++) {
                if (k < cnt) {
                    int sv = __shfl(ss, gbase + k, 64);
                    ushort4 v = ((const ushort4*)(z2 + (size_t)sv * OUTF))[gl];
                    float4* a = (k & 3) == 0 ? &a0 : (k & 3) == 1 ? &a1 : (k & 3) == 2 ? &a2 : &a3;
                    a->x += bf2f(v.x); a->y += bf2f(v.y); a->z += bf2f(v.z); a->w += bf2f(v.w);
                }
            }
        }
        float4 lg;
        lg.x = fmaf(a0.x + a1.x + a2.x + a3.x, di, bvec.x);
        lg.y = fmaf(a0.y + a1.y + a2.y + a3.y, di, bvec.y);
        lg.z = fmaf(a0.z + a1.z + a2.z + a3.z, di, bvec.z);
        lg.w = fmaf(a0.w + a1.w + a2.w + a3.w, di, bvec.w);
        if (i < N) ((float4*)(logits + (size_t)i * OUTF))[gl] = lg;
        // softmax + entropy over 32 logits spread across 8 lanes x 4
        float m4 = fmaxf(fmaxf(lg.x, lg.y), fmaxf(lg.z, lg.w));
        for (int off = 4; off > 0; off >>= 1) m4 = fmaxf(m4, __shfl_xor(m4, off, 8));
        float p0 = expf(lg.x - m4), p1 = expf(lg.y - m4), p2 = expf(lg.z - m4), p3 = expf(lg.w - m4);
        float s4 = p0 + p1 + p2 + p3;
        for (int off = 4; off > 0; off >>= 1) s4 += __shfl_xor(s4, off, 8);
        float inv = 1.0f / s4;
        float t0 = p0 * inv, t1v = p1 * inv, t2v = p2 * inv, t3 = p3 * inv;
        float e4 = t0 * logf(t0 + 1e-9f) + t1v * logf(t1v + 1e-9f) + t2v * logf(t2v + 1e-9f) + t3 * logf(t3 + 1e-9f);
        for (int off = 4; off > 0; off >>= 1) e4 += __shfl_xor(e4, off, 8);
        float w = 1.0f / (-e4 + 1e-10f);
        if (i < N) {
            if (gl == 0) wraw[i] = w;
            mn = fminf(mn, w);
            mx = fmaxf(mx, w);
        }
    }
    for (int off = 32; off > 0; off >>= 1) {
        mn = fminf(mn, __shfl_xor(mn, off, 64));
        mx = fmaxf(mx, __shfl_xor(mx, off, 64));
    }
    if (lane == 0) { smn[wave] = mn; smx[wave] = mx; }
    __syncthreads();
    if (tid == 0) {
        float a = fminf(fminf(smn[0], smn[1]), fminf(smn[2], smn[3]));
        float b = fmaxf(fmaxf(smx[0], smx[1]), fmaxf(smx[2], smx[3]));
        atomicMin(&redmm[33], fenc(a));
        atomicMax(&redmm[34], fenc(b));
    }
}

__global__ __launch_bounds__(256) void k_weight(const float* __restrict__ logits, const float* __restrict__ wraw,
                                                float* __restrict__ red, int N) {
    const unsigned* mm = (const unsigned*)red;
    float mn = fdec(mm[33]), mx = fdec(mm[34]);
    float inv = 1.0f / (mx - mn);
    int c = threadIdx.x & 31;
    int g = threadIdx.x >> 5;  // 8 row-groups
    float acc = 0.0f, es = 0.0f;
    for (int r = blockIdx.x * 8 + g; r < N; r += gridDim.x * 8) {
        float e = expf((wraw[r] - mn) * inv);
        acc += e * logits[(size_t)r * OUTF + c];
        if (c == 0) es += e;
    }
    __shared__ float sa[8][OUTF];
    __shared__ float se[8];
    sa[g][c] = acc;
    if (c == 0) se[g] = es;
    __syncthreads();
    if (g == 0) {
        float t = sa[0][c];
#pragma unroll
        for (int i = 1; i < 8; i++) t += sa[i][c];
        unsafeAtomicAdd(&red[c], t);
        if (c == 0) {
            float u = 0.0f;
#pragma unroll
            for (int i = 0; i < 8; i++) u += se[i];
            unsafeAtomicAdd(&red[32], u);
        }
    }
}

__global__ void k_final(const float* __restrict__ red, const float* __restrict__ w3,
                        const float* __restrict__ b3, float* __restrict__ out) {
    int j = threadIdx.x;  // 64 threads
    float s = red[32];
    float o = b3[j];
#pragma unroll
    for (int cc = 0; cc < OUTF; cc++) o += (red[cc] / s) * w3[cc * F + j];
    out[j] = o;
}

extern "C" void kernel_launch(void* const* d_in, const int* in_sizes, int n_in,
                              void* d_out, int out_size, void* d_ws, size_t ws_size,
                              hipStream_t stream) {
    const float* x     = (const float*)d_in[0];
    const int*   ei    = (const int*)d_in[1];
    const float* W1    = (const float*)d_in[2];
    const float* b1    = (const float*)d_in[3];
    const float* gamma = (const float*)d_in[4];
    const float* beta  = (const float*)d_in[5];
    const float* W2    = (const float*)d_in[6];
    const float* b2    = (const float*)d_in[7];
    const float* l2w   = (const float*)d_in[8];
    const float* l2b   = (const float*)d_in[9];
    const float* l3w   = (const float*)d_in[10];
    const float* l3b   = (const float*)d_in[11];

    int N = in_sizes[0] / F;
    int E = in_sizes[1] / 2;
    const int* src = ei;
    const int* dst = ei + E;
    int NBK = (N + 255) >> 8;  // 391 buckets of 256 nodes (<=512 assumed)

    // workspace layout (16B-aligned chunks)
    char* p = (char*)d_ws;
    int* hist = (int*)p;                p += (size_t)PB * NBK * 4;
    int* btot = (int*)p;                p += 512 * 4;
    int* bbase = (int*)p;               p += 516 * 4;
    unsigned* bucketArr = (unsigned*)p; p += (size_t)E * 4;
    int4* meta = (int4*)p;              p += (size_t)N * 16;
    int* eidx = (int*)p;                p += (size_t)E * 4;
    float* red = (float*)p;             p += 64 * 4;
    float* w2l2 = (float*)p;            p += F * OUTF * 4;
    float* b2l2 = (float*)p;            p += OUTF * 4 + 32;
    unsigned short* xbf = (unsigned short*)p;  p += (size_t)N * F * 2;  // aliased by z2
    unsigned short* t1 = (unsigned short*)p;   p += (size_t)N * F * 2;  // aliased by logits
    float* wraw = (float*)p;            p += (size_t)N * 4;
    unsigned short* z2 = xbf;           // xbf dead after conv1agg
    float* logits = (float*)t1;         // t1 dead after k_z

    // setup + privatized counting-sort CSR build
    k_fuse<<<8, 256, 0, stream>>>(W2, b2, l2w, l2b, w2l2, b2l2, red);
    k_hist<<<PB, 256, 0, stream>>>(dst, hist, E, NBK);
    k_hscan1<<<NBK, PB, 0, stream>>>(hist, btot, NBK);
    k_hscan2<<<1, 512, 0, stream>>>(btot, bbase, NBK);
    k_place<<<PB, 256, 0, stream>>>(src, dst, hist, bbase, bucketArr, E, NBK);
    k_binsort<<<NBK, 256, 0, stream>>>(bucketArr, bbase, eidx, meta, N);
    k_prescale<<<(N * 16 + 255) / 256, 256, 0, stream>>>((const float4*)x, meta, (ushort4*)xbf, N * 16);

    // convs
    k_conv1agg<<<2048, 256, 0, stream>>>(xbf, meta, eidx, t1, N);
    k_z<<<1024, 256, 0, stream>>>(t1, meta, W1, b1, gamma, beta, w2l2, z2, N);
    k_conv2agg<<<2048, 256, 0, stream>>>(z2, meta, eidx, b2l2, logits, wraw, (unsigned*)red, N);

    // pooling head
    k_weight<<<1024, 256, 0, stream>>>(logits, wraw, red, N);
    k_final<<<1, 64, 0, stream>>>(red, l3w, l3b, (float*)d_out);
}